// Round 1
// baseline (1617.909 us; speedup 1.0000x reference)
//
#include <hip/hip_runtime.h>
#include <hip/hip_bf16.h>

#define T_TOK 4096
#define D_DIM 1024
#define E_NUM 8
#define F_DIM 4096

typedef __bf16 bf16_t;
typedef bf16_t bf16x8 __attribute__((ext_vector_type(8)));
typedef float f32x4 __attribute__((ext_vector_type(4)));

// ---------------- workspace layout (bytes) ----------------
// h:      bf16 [8192][4096]  = 64 MiB
// rowv:   f32  [8192][1024]  = 32 MiB
// scores: f32  [4096][8]
// tok_tmp:int  [8][4096]
// sc_tmp: f32  [8][4096]
// tok2row:int  [4096][2]
// counts: int[8], offsets: int[8]
#define WS_H      0ull
#define WS_ROWV   (WS_H      + 8192ull*4096*2)
#define WS_SCORES (WS_ROWV   + 8192ull*1024*4)
#define WS_TOK    (WS_SCORES + 4096ull*8*4)
#define WS_SC     (WS_TOK    + 8ull*4096*4)
#define WS_T2R    (WS_SC     + 8ull*4096*4)
#define WS_CNT    (WS_T2R    + 4096ull*2*4)
#define WS_OFF    (WS_CNT    + 32ull)

// ---------------- router: one wave per token ----------------
__global__ __launch_bounds__(256) void router_k(
    const float* __restrict__ x, const float* __restrict__ noise,
    const float* __restrict__ gate_w, const float* __restrict__ gate_b,
    const float* __restrict__ noise_w, const float* __restrict__ noise_b,
    float* __restrict__ scores, int* __restrict__ tok_tmp,
    float* __restrict__ sc_tmp, int* __restrict__ tok2row, int* __restrict__ counts)
{
    int t = blockIdx.x * 4 + (threadIdx.x >> 6);
    int lane = threadIdx.x & 63;
    const float* xr = x + (size_t)t * D_DIM;
    float acc[8] = {0,0,0,0,0,0,0,0};
    for (int d = lane; d < D_DIM; d += 64) {
        float xv = xr[d];
#pragma unroll
        for (int e = 0; e < 8; e++)
            acc[e] += xv * (gate_w[d*8+e] + noise_w[d*8+e]);
    }
#pragma unroll
    for (int e = 0; e < 8; e++) {
#pragma unroll
        for (int m = 1; m < 64; m <<= 1)
            acc[e] += __shfl_xor(acc[e], m);
    }
    // every lane now has full sums; compute redundantly (deterministic)
    float lg[8];
#pragma unroll
    for (int e = 0; e < 8; e++)
        lg[e] = acc[e] + gate_b[e] + noise_b[e] + noise[t*8+e];
    int e1 = 0; float v1 = lg[0];
#pragma unroll
    for (int e = 1; e < 8; e++) if (lg[e] > v1) { v1 = lg[e]; e1 = e; }
    int e2 = -1; float v2 = -INFINITY;
#pragma unroll
    for (int e = 0; e < 8; e++) if (e != e1 && lg[e] > v2) { v2 = lg[e]; e2 = e; }
    float ex = expf(v2 - v1);
    float den = 1.0f + ex;
    float s1 = 1.0f / den, s2 = ex / den;
    if (lane < 8)
        scores[t*8+lane] = (lane==e1) ? s1 : ((lane==e2) ? s2 : 0.0f);
    if (lane == 0) {
        int p1 = atomicAdd(&counts[e1], 1);
        tok_tmp[e1*T_TOK + p1] = t; sc_tmp[e1*T_TOK + p1] = s1;
        tok2row[t*2]   = (e1<<16) | p1;
        int p2 = atomicAdd(&counts[e2], 1);
        tok_tmp[e2*T_TOK + p2] = t; sc_tmp[e2*T_TOK + p2] = s2;
        tok2row[t*2+1] = (e2<<16) | p2;
    }
}

__global__ void prefix_k(const int* __restrict__ counts, int* __restrict__ offsets) {
    if (threadIdx.x == 0) {
        int o = 0;
        for (int e = 0; e < 8; e++) { offsets[e] = o; o += counts[e]; }
    }
}

__global__ __launch_bounds__(256) void aux_k(const float* __restrict__ scores,
                                             float* __restrict__ out_aux) {
    __shared__ float part[256];
    int i = threadIdx.x;
    int e = i & 7, g = i >> 3;
    float s = 0.f;
    for (int t = g; t < T_TOK; t += 32) s += scores[t*8+e];
    part[i] = s; __syncthreads();
    for (int st = 128; st >= 8; st >>= 1) {
        if (i < st) part[i] += part[i+st];
        __syncthreads();
    }
    if (i == 0) {
        float aux = 0.f;
        for (int ee = 0; ee < 8; ee++) {
            float imp = part[ee] * (1.0f / (float)T_TOK);
            aux += 0.125f * (logf(0.125f) - logf(imp + 1e-8f));
        }
        *out_aux = aux;
    }
}

// ---------------- GEMM common ----------------
#define BM 128
#define BN 128
#define BK 32
#define LDA 40    // bf16 elems per LDS row (padded)
#define LDCB 136  // bf16 C-transpose stride (passA)
#define LDCF 68   // f32 half C-transpose stride (passB)
#define SMEM_BYTES 35328  // 34816 (Ct) + 512 (rowtok/rowsc)

// pass A: h[row] = silu(x[tok] @ w1[e] + b1[e]), bf16 out
__global__ __launch_bounds__(256) void ffn1_k(
    const float* __restrict__ x, const float* __restrict__ w1, const float* __restrict__ b1,
    const int* __restrict__ tok_tmp, const int* __restrict__ counts,
    const int* __restrict__ offsets, bf16_t* __restrict__ h)
{
    int e  = blockIdx.x >> 5;
    int mt = blockIdx.x & 31;
    int nt = blockIdx.y;
    int ne = counts[e];
    if (mt * BM >= ne) return;
    int nb = nt * BN;
    const float* W = w1 + (size_t)e * D_DIM * F_DIM;

    __shared__ alignas(16) char smem[SMEM_BYTES];
    bf16_t* As = (bf16_t*)smem;               // [128][40]
    bf16_t* Bs = (bf16_t*)(smem + 10240);     // [128][40]  (n-major, k contiguous)
    int* rowtok = (int*)(smem + 34816);       // [128]

    int tid = threadIdx.x;
    if (tid < 128) {
        int r = mt*BM + tid;
        rowtok[tid] = (r < ne) ? tok_tmp[e*T_TOK + r] : -1;
    }
    __syncthreads();

    f32x4 acc[4][4] = {};
    int wave = tid >> 6, lane = tid & 63;
    int wm = (wave & 1) * 64, wn = (wave >> 1) * 64;
    int fr = lane & 15, fk = (lane >> 4) * 8;
    int sr = tid >> 1, sh = (tid & 1) * 16;        // A staging: row, 16-float chunk
    int bn_ = tid & 127, bk_ = (tid >> 7) * 16;    // B staging: col n, 16-k chunk

    for (int k0 = 0; k0 < D_DIM; k0 += BK) {
        { // stage A (gathered x rows, f32 -> bf16)
            int tok = rowtok[sr];
            union { bf16_t u[16]; bf16x8 v[2]; } pk;
            if (tok >= 0) {
                const float* src = x + (size_t)tok * D_DIM + k0 + sh;
#pragma unroll
                for (int j = 0; j < 16; j++) pk.u[j] = (bf16_t)src[j];
            } else {
#pragma unroll
                for (int j = 0; j < 16; j++) pk.u[j] = (bf16_t)0.0f;
            }
            *(bf16x8*)(As + sr*LDA + sh)     = pk.v[0];
            *(bf16x8*)(As + sr*LDA + sh + 8) = pk.v[1];
        }
        { // stage B transposed: Bs[n][k] <- W[k][n], f32 -> bf16
            union { bf16_t u[16]; bf16x8 v[2]; } pk;
            const float* src = W + (size_t)(k0 + bk_) * F_DIM + nb + bn_;
#pragma unroll
            for (int j = 0; j < 16; j++) pk.u[j] = (bf16_t)src[(size_t)j * F_DIM];
            *(bf16x8*)(Bs + bn_*LDA + bk_)     = pk.v[0];
            *(bf16x8*)(Bs + bn_*LDA + bk_ + 8) = pk.v[1];
        }
        __syncthreads();
        bf16x8 af[4], bfr[4];
#pragma unroll
        for (int i = 0; i < 4; i++) af[i]  = *(bf16x8*)(As + (wm + i*16 + fr)*LDA + fk);
#pragma unroll
        for (int i = 0; i < 4; i++) bfr[i] = *(bf16x8*)(Bs + (wn + i*16 + fr)*LDA + fk);
#pragma unroll
        for (int mi = 0; mi < 4; mi++)
#pragma unroll
            for (int ni = 0; ni < 4; ni++)
                acc[mi][ni] = __builtin_amdgcn_mfma_f32_16x16x32_bf16(af[mi], bfr[ni], acc[mi][ni], 0, 0, 0);
        __syncthreads();
    }

    // epilogue: +b1, silu, bf16, LDS transpose for coalesced stores
    bf16_t* Ct = (bf16_t*)smem;  // [128][136], aliases As/Bs (done with them)
    const float* b1e = b1 + (size_t)e * F_DIM + nb;
#pragma unroll
    for (int mi = 0; mi < 4; mi++) {
        int row = wm + mi*16 + ((lane >> 4) << 2);
#pragma unroll
        for (int ni = 0; ni < 4; ni++) {
            int col = wn + ni*16 + fr;
            float bb = b1e[col];
#pragma unroll
            for (int r = 0; r < 4; r++) {
                float v = acc[mi][ni][r] + bb;
                float sv = v / (1.0f + expf(-v));
                Ct[(row + r)*LDCB + col] = (bf16_t)sv;
            }
        }
    }
    __syncthreads();
    {
        int row = tid >> 1, seg = (tid & 1) * 64;
        if (mt*BM + row < ne) {
            int grow = offsets[e] + mt*BM + row;
            bf16_t* dst = h + (size_t)grow * F_DIM + nb + seg;
#pragma unroll
            for (int j = 0; j < 8; j++)
                *(bf16x8*)(dst + j*8) = *(bf16x8*)(Ct + row*LDCB + seg + j*8);
        }
    }
}

// pass B: rowv[row] = score * (h[row] @ w2[e] + b2[e]), f32 out
__global__ __launch_bounds__(256) void ffn2_k(
    const bf16_t* __restrict__ h, const float* __restrict__ w2, const float* __restrict__ b2,
    const float* __restrict__ sc_tmp, const int* __restrict__ counts,
    const int* __restrict__ offsets, float* __restrict__ rowv)
{
    int e  = blockIdx.x >> 5;
    int mt = blockIdx.x & 31;
    int nt = blockIdx.y;   // 0..7
    int ne = counts[e];
    if (mt * BM >= ne) return;
    int nb = nt * BN;
    int off = offsets[e];
    const float* W = w2 + (size_t)e * F_DIM * D_DIM;

    __shared__ alignas(16) char smem[SMEM_BYTES];
    bf16_t* As = (bf16_t*)smem;
    bf16_t* Bs = (bf16_t*)(smem + 10240);
    float* rowsc = (float*)(smem + 34816);   // [128]

    int tid = threadIdx.x;
    if (tid < 128) {
        int r = mt*BM + tid;
        rowsc[tid] = (r < ne) ? sc_tmp[e*T_TOK + r] : 0.0f;
    }
    __syncthreads();

    f32x4 acc[4][4] = {};
    int wave = tid >> 6, lane = tid & 63;
    int wm = (wave & 1) * 64, wnn = wave >> 1;
    int fr = lane & 15, fk = (lane >> 4) * 8;
    int sr = tid >> 1, sh = (tid & 1) * 16;
    int bn_ = tid & 127, bk_ = (tid >> 7) * 16;
    bool arow_valid = (mt*BM + sr) < ne;
    const bf16_t* asrc0 = h + (size_t)(off + mt*BM + sr) * F_DIM + sh;

    for (int k0 = 0; k0 < F_DIM; k0 += BK) {
        { // stage A from h (already bf16)
            bf16x8 v0, v1;
            if (arow_valid) {
                v0 = *(const bf16x8*)(asrc0 + k0);
                v1 = *(const bf16x8*)(asrc0 + k0 + 8);
            } else {
                v0 = (bf16x8)(bf16_t)0.0f; v1 = (bf16x8)(bf16_t)0.0f;
            }
            *(bf16x8*)(As + sr*LDA + sh)     = v0;
            *(bf16x8*)(As + sr*LDA + sh + 8) = v1;
        }
        { // stage B transposed: Bs[n][k] <- W[k][n]
            union { bf16_t u[16]; bf16x8 v[2]; } pk;
            const float* src = W + (size_t)(k0 + bk_) * D_DIM + nb + bn_;
#pragma unroll
            for (int j = 0; j < 16; j++) pk.u[j] = (bf16_t)src[(size_t)j * D_DIM];
            *(bf16x8*)(Bs + bn_*LDA + bk_)     = pk.v[0];
            *(bf16x8*)(Bs + bn_*LDA + bk_ + 8) = pk.v[1];
        }
        __syncthreads();
        bf16x8 af[4], bfr[4];
#pragma unroll
        for (int i = 0; i < 4; i++) af[i]  = *(bf16x8*)(As + (wm + i*16 + fr)*LDA + fk);
#pragma unroll
        for (int i = 0; i < 4; i++) bfr[i] = *(bf16x8*)(Bs + (wnn*64 + i*16 + fr)*LDA + fk);
#pragma unroll
        for (int mi = 0; mi < 4; mi++)
#pragma unroll
            for (int ni = 0; ni < 4; ni++)
                acc[mi][ni] = __builtin_amdgcn_mfma_f32_16x16x32_bf16(af[mi], bfr[ni], acc[mi][ni], 0, 0, 0);
        __syncthreads();
    }

    // epilogue: +b2, *score, f32 out via LDS in two column-halves (32KB buffer)
    const float* b2e = b2 + (size_t)e * D_DIM + nb;
    float* Ctf = (float*)smem;  // [128][68] f32
    for (int half = 0; half < 2; half++) {
        if (wnn == half) {
#pragma unroll
            for (int mi = 0; mi < 4; mi++) {
                int row = wm + mi*16 + ((lane >> 4) << 2);
#pragma unroll
                for (int ni = 0; ni < 4; ni++) {
                    int lcol = ni*16 + fr;
                    float bb = b2e[half*64 + lcol];
#pragma unroll
                    for (int r = 0; r < 4; r++) {
                        float v = (acc[mi][ni][r] + bb) * rowsc[row + r];
                        Ctf[(row + r)*LDCF + lcol] = v;
                    }
                }
            }
        }
        __syncthreads();
        {
            int row = tid >> 1, seg = (tid & 1) * 32;
            if (mt*BM + row < ne) {
                float* dst = rowv + (size_t)(off + mt*BM + row) * D_DIM + nb + half*64 + seg;
#pragma unroll
                for (int j = 0; j < 8; j++)
                    *(f32x4*)(dst + j*4) = *(f32x4*)(Ctf + row*LDCF + seg + j*4);
            }
        }
        __syncthreads();
    }
}

// ---------------- combine: out[t] = rowv[r0] + rowv[r1] ----------------
__global__ __launch_bounds__(256) void combine_k(
    const float* __restrict__ rowv, const int* __restrict__ tok2row,
    const int* __restrict__ offsets, float* __restrict__ out)
{
    int t = blockIdx.x;
    int p0 = tok2row[t*2], p1 = tok2row[t*2+1];
    int r0 = offsets[p0 >> 16] + (p0 & 0xffff);
    int r1 = offsets[p1 >> 16] + (p1 & 0xffff);
    int d = threadIdx.x * 4;
    f32x4 a = *(const f32x4*)(rowv + (size_t)r0 * D_DIM + d);
    f32x4 b = *(const f32x4*)(rowv + (size_t)r1 * D_DIM + d);
    *(f32x4*)(out + (size_t)t * D_DIM + d) = a + b;
}

extern "C" void kernel_launch(void* const* d_in, const int* in_sizes, int n_in,
                              void* d_out, int out_size, void* d_ws, size_t ws_size,
                              hipStream_t stream) {
    const float* x       = (const float*)d_in[0];
    const float* noise   = (const float*)d_in[1];
    const float* gate_w  = (const float*)d_in[2];
    const float* gate_b  = (const float*)d_in[3];
    const float* noise_w = (const float*)d_in[4];
    const float* noise_b = (const float*)d_in[5];
    const float* w1      = (const float*)d_in[6];
    const float* b1      = (const float*)d_in[7];
    const float* w2      = (const float*)d_in[8];
    const float* b2      = (const float*)d_in[9];
    float* out = (float*)d_out;
    char* ws = (char*)d_ws;

    bf16_t* h       = (bf16_t*)(ws + WS_H);
    float*  rowv    = (float*) (ws + WS_ROWV);
    float*  scores  = (float*) (ws + WS_SCORES);
    int*    tok_tmp = (int*)   (ws + WS_TOK);
    float*  sc_tmp  = (float*) (ws + WS_SC);
    int*    tok2row = (int*)   (ws + WS_T2R);
    int*    counts  = (int*)   (ws + WS_CNT);
    int*    offsets = (int*)   (ws + WS_OFF);

    hipMemsetAsync(ws + WS_CNT, 0, 64, stream);
    router_k<<<T_TOK/4, 256, 0, stream>>>(x, noise, gate_w, gate_b, noise_w, noise_b,
                                          scores, tok_tmp, sc_tmp, tok2row, counts);
    prefix_k<<<1, 64, 0, stream>>>(counts, offsets);
    aux_k<<<1, 256, 0, stream>>>(scores, out + (size_t)T_TOK * D_DIM);
    ffn1_k<<<dim3(E_NUM*32, F_DIM/BN), 256, 0, stream>>>(x, w1, b1, tok_tmp, counts, offsets, h);
    ffn2_k<<<dim3(E_NUM*32, D_DIM/BN), 256, 0, stream>>>(h, w2, b2, sc_tmp, counts, offsets, rowv);
    combine_k<<<T_TOK, 256, 0, stream>>>(rowv, tok2row, offsets, out);
}

// Round 2
// 742.226 us; speedup vs baseline: 2.1798x; 2.1798x over previous
//
#include <hip/hip_runtime.h>
#include <hip/hip_bf16.h>
#include <cstdint>
#include <cstddef>

#define T_TOK 4096
#define D_DIM 1024
#define E_NUM 8
#define F_DIM 4096

typedef __bf16 bf16_t;
typedef bf16_t bf16x8 __attribute__((ext_vector_type(8)));
typedef float f32x4 __attribute__((ext_vector_type(4)));

// async 16B global->LDS. LDS dest is wave-uniform base; HW adds lane*16.
__device__ __forceinline__ void gl_lds16(const void* g, void* l) {
    __builtin_amdgcn_global_load_lds(
        (const __attribute__((address_space(1))) unsigned int*)g,
        (__attribute__((address_space(3))) unsigned int*)l,
        16, 0, 0);
}

// ================= FAST-PATH workspace layout (bytes) =================
// w1t : bf16 image [e][nt=32][ks=32][n=128][kc=4][8]   = 64 MiB
// w2t : bf16 image [e][nt=8][ks=128][n=128][kc=4][8]   = 64 MiB
// h_t : bf16 image [rowblk<=72][ks=128][row=128][kc=4][8] = 72 MiB
// x_bf: bf16 [4096][1024]                               = 8 MiB
// rowv: f32 [8192][1024]                                = 32 MiB
#define F_W1T    0ull
#define F_W2T    67108864ull
#define F_HT     134217728ull
#define F_XBF    209715200ull
#define F_ROWV   218103808ull
#define F_SCORES 251658240ull
#define F_TOK    (F_SCORES + 131072ull)
#define F_SC     (F_TOK    + 131072ull)
#define F_T2R    (F_SC     + 131072ull)
#define F_CNT    (F_T2R    + 32768ull)
#define F_OFF    (F_CNT    + 32ull)
#define F_BLK    (F_OFF    + 32ull)
#define FAST_NEED (F_BLK + 32ull)

// ================= FALLBACK (round-1) workspace layout =================
#define WS_H      0ull
#define WS_ROWV   (WS_H      + 8192ull*4096*2)
#define WS_SCORES (WS_ROWV   + 8192ull*1024*4)
#define WS_TOK    (WS_SCORES + 4096ull*8*4)
#define WS_SC     (WS_TOK    + 8ull*4096*4)
#define WS_T2R    (WS_SC     + 8ull*4096*4)
#define WS_CNT    (WS_T2R    + 4096ull*2*4)
#define WS_OFF    (WS_CNT    + 32ull)
#define WS_BLK    (WS_OFF    + 32ull)

// ---------------- router: one wave per token (shared) ----------------
__global__ __launch_bounds__(256) void router_k(
    const float* __restrict__ x, const float* __restrict__ noise,
    const float* __restrict__ gate_w, const float* __restrict__ gate_b,
    const float* __restrict__ noise_w, const float* __restrict__ noise_b,
    float* __restrict__ scores, int* __restrict__ tok_tmp,
    float* __restrict__ sc_tmp, int* __restrict__ tok2row, int* __restrict__ counts)
{
    int t = blockIdx.x * 4 + (threadIdx.x >> 6);
    int lane = threadIdx.x & 63;
    const float* xr = x + (size_t)t * D_DIM;
    float acc[8] = {0,0,0,0,0,0,0,0};
    for (int d = lane; d < D_DIM; d += 64) {
        float xv = xr[d];
#pragma unroll
        for (int e = 0; e < 8; e++)
            acc[e] += xv * (gate_w[d*8+e] + noise_w[d*8+e]);
    }
#pragma unroll
    for (int e = 0; e < 8; e++) {
#pragma unroll
        for (int m = 1; m < 64; m <<= 1)
            acc[e] += __shfl_xor(acc[e], m);
    }
    float lg[8];
#pragma unroll
    for (int e = 0; e < 8; e++)
        lg[e] = acc[e] + gate_b[e] + noise_b[e] + noise[t*8+e];
    int e1 = 0; float v1 = lg[0];
#pragma unroll
    for (int e = 1; e < 8; e++) if (lg[e] > v1) { v1 = lg[e]; e1 = e; }
    int e2 = -1; float v2 = -INFINITY;
#pragma unroll
    for (int e = 0; e < 8; e++) if (e != e1 && lg[e] > v2) { v2 = lg[e]; e2 = e; }
    float ex = expf(v2 - v1);
    float den = 1.0f + ex;
    float s1 = 1.0f / den, s2 = ex / den;
    if (lane < 8)
        scores[t*8+lane] = (lane==e1) ? s1 : ((lane==e2) ? s2 : 0.0f);
    if (lane == 0) {
        int p1 = atomicAdd(&counts[e1], 1);
        tok_tmp[e1*T_TOK + p1] = t; sc_tmp[e1*T_TOK + p1] = s1;
        tok2row[t*2]   = (e1<<16) | p1;
        int p2 = atomicAdd(&counts[e2], 1);
        tok_tmp[e2*T_TOK + p2] = t; sc_tmp[e2*T_TOK + p2] = s2;
        tok2row[t*2+1] = (e2<<16) | p2;
    }
}

__global__ void prefix_k(const int* __restrict__ counts, int* __restrict__ offsets,
                         int* __restrict__ blk_off) {
    if (threadIdx.x == 0) {
        int o = 0, b = 0;
        for (int e = 0; e < 8; e++) {
            offsets[e] = o; blk_off[e] = b;
            o += counts[e]; b += (counts[e] + 127) >> 7;
        }
    }
}

__global__ __launch_bounds__(256) void aux_k(const float* __restrict__ scores,
                                             float* __restrict__ out_aux) {
    __shared__ float part[256];
    int i = threadIdx.x;
    int e = i & 7, g = i >> 3;
    float s = 0.f;
    for (int t = g; t < T_TOK; t += 32) s += scores[t*8+e];
    part[i] = s; __syncthreads();
    for (int st = 128; st >= 8; st >>= 1) {
        if (i < st) part[i] += part[i+st];
        __syncthreads();
    }
    if (i == 0) {
        float aux = 0.f;
        for (int ee = 0; ee < 8; ee++) {
            float imp = part[ee] * (1.0f / (float)T_TOK);
            aux += 0.125f * (logf(0.125f) - logf(imp + 1e-8f));
        }
        *out_aux = aux;
    }
}

// ---------------- prep kernels (fast path) ----------------
// pre-tile weights f32 -> bf16 LDS-image layout with baked XOR swizzle:
// chunk (n, kc_phys) holds src k-chunk kc_data = kc_phys ^ ((n>>1)&3)
__global__ __launch_bounds__(256) void prep_w_k(
    const float* __restrict__ src, bf16_t* __restrict__ dst,
    int ksb, int ntb, int Kdim, int Ndim)
{
    size_t cid = (size_t)blockIdx.x * 256 + threadIdx.x;
    int kc = cid & 3;
    int n  = (cid >> 2) & 127;
    int ks = (cid >> 9) & ((1 << ksb) - 1);
    int nt = (cid >> (9 + ksb)) & ((1 << ntb) - 1);
    int e  = (int)(cid >> (9 + ksb + ntb));
    int kcd = kc ^ ((n >> 1) & 3);
    int k0 = ks * 32 + kcd * 8;
    const float* s = src + ((size_t)e * Kdim + k0) * Ndim + nt * 128 + n;
    union { bf16_t u[8]; bf16x8 v; } pk;
#pragma unroll
    for (int j = 0; j < 8; j++) pk.u[j] = (bf16_t)s[(size_t)j * Ndim];
    *(bf16x8*)(dst + cid * 8) = pk.v;
}

__global__ __launch_bounds__(256) void prep_x_k(const float* __restrict__ x,
                                                bf16_t* __restrict__ xb) {
    size_t i = ((size_t)blockIdx.x * 256 + threadIdx.x) * 8;
    f32x4 a = *(const f32x4*)(x + i);
    f32x4 b = *(const f32x4*)(x + i + 4);
    union { bf16_t u[8]; bf16x8 v; } pk;
#pragma unroll
    for (int j = 0; j < 4; j++) { pk.u[j] = (bf16_t)a[j]; pk.u[4+j] = (bf16_t)b[j]; }
    *(bf16x8*)(xb + i) = pk.v;
}

// ---------------- fast GEMM 1: h_t = silu(x @ w1 + b1) ----------------
__global__ __launch_bounds__(256) void ffn1_fast_k(
    const bf16_t* __restrict__ xb, const bf16_t* __restrict__ w1t,
    const float* __restrict__ b1, const int* __restrict__ tok_tmp,
    const int* __restrict__ counts, const int* __restrict__ blk_off,
    char* __restrict__ h_t)
{
    int bx = blockIdx.x;
    int nt = bx & 31, mt = (bx >> 5) & 31, e = bx >> 10;
    int ne = counts[e];
    if (mt * 128 >= ne) return;

    __shared__ alignas(16) char smem[16384];
    int tid = threadIdx.x, w = tid >> 6, l = tid & 63;

    // staging: wave w issue j covers LDS rows w*32+j*16 .. +16
    int srow0 = w * 32 + (l >> 2);
    int kcd = (l & 3) ^ ((l >> 3) & 3);      // chunk ^ swizzle(row), same for both issues
    int g0r = mt * 128 + srow0, g1r = g0r + 16;
    int tok0 = tok_tmp[e * T_TOK + (g0r < ne ? g0r : 0)];
    int tok1 = tok_tmp[e * T_TOK + (g1r < ne ? g1r : 0)];
    const char* gA0 = (const char*)(xb + (size_t)tok0 * D_DIM + kcd * 8);
    const char* gA1 = (const char*)(xb + (size_t)tok1 * D_DIM + kcd * 8);
    const char* gB0 = (const char*)w1t + ((size_t)(e * 32 + nt) * 32) * 8192
                      + w * 2048 + l * 16;
    const char* gB1 = gB0 + 1024;
    char* lA0 = smem + w * 2048;             // wave-uniform
    char* lA1 = lA0 + 1024;
    char* lB0 = smem + 8192 + w * 2048;
    char* lB1 = lB0 + 1024;

    // fragment LDS offsets (constant across k-steps)
    int fr = l & 15, kq = l >> 4;
    int csel = (kq ^ ((fr >> 1) & 3)) << 4;
    int wm = (w & 1) * 64, wn = (w >> 1) * 64;
    int aoff[4], boff[4];
#pragma unroll
    for (int i = 0; i < 4; i++) {
        aoff[i] = (wm + i * 16 + fr) * 64 + csel;
        boff[i] = 8192 + (wn + i * 16 + fr) * 64 + csel;
    }

    f32x4 acc[4][4] = {};
    for (int ks = 0; ks < 32; ks++) {
        gl_lds16(gA0, lA0); gl_lds16(gA1, lA1);
        gl_lds16(gB0, lB0); gl_lds16(gB1, lB1);
        gA0 += 64; gA1 += 64; gB0 += 8192; gB1 += 8192;
        __syncthreads();
        bf16x8 af[4], bf[4];
#pragma unroll
        for (int i = 0; i < 4; i++) af[i] = *(const bf16x8*)(smem + aoff[i]);
#pragma unroll
        for (int i = 0; i < 4; i++) bf[i] = *(const bf16x8*)(smem + boff[i]);
#pragma unroll
        for (int mi = 0; mi < 4; mi++)
#pragma unroll
            for (int ni = 0; ni < 4; ni++)
                acc[mi][ni] = __builtin_amdgcn_mfma_f32_16x16x32_bf16(af[mi], bf[ni], acc[mi][ni], 0, 0, 0);
        __syncthreads();
    }

    // epilogue: +b1, silu, write 4 sub-tile images (32 cols each) into h_t
    int quad = l >> 4;
    size_t htBase = (size_t)(blk_off[e] + mt) * 1048576ull;
    const float* b1e = b1 + (size_t)e * F_DIM + nt * 128;
    for (int rnd = 0; rnd < 4; rnd++) {
        if ((w >> 1) == (rnd >> 1)) {
            int nb0 = (rnd & 1) * 2;
#pragma unroll
            for (int nn = 0; nn < 2; nn++) {
                int cl = nn * 16 + fr;
                float bb = b1e[rnd * 32 + cl];
#pragma unroll
                for (int mi = 0; mi < 4; mi++) {
                    int rbase = wm + mi * 16 + quad * 4;
#pragma unroll
                    for (int r = 0; r < 4; r++) {
                        int row = rbase + r;
                        float v = acc[mi][nb0 + nn][r] + bb;
                        v = v / (1.0f + expf(-v));
                        int off = row * 64 + (((cl >> 3) ^ ((row >> 1) & 3)) << 4) + ((cl & 7) << 1);
                        *(bf16_t*)(smem + off) = (bf16_t)v;
                    }
                }
            }
        }
        __syncthreads();
        {
            size_t sub = htBase + (size_t)(nt * 4 + rnd) * 8192;
            *(f32x4*)(h_t + sub + tid * 16)         = *(const f32x4*)(smem + tid * 16);
            *(f32x4*)(h_t + sub + (tid + 256) * 16) = *(const f32x4*)(smem + (tid + 256) * 16);
        }
        __syncthreads();
    }
}

// ---------------- fast GEMM 2: rowv = score*(h @ w2 + b2) ----------------
__global__ __launch_bounds__(256) void ffn2_fast_k(
    const char* __restrict__ h_t, const bf16_t* __restrict__ w2t,
    const float* __restrict__ b2, const float* __restrict__ sc_tmp,
    const int* __restrict__ counts, const int* __restrict__ offsets,
    const int* __restrict__ blk_off, float* __restrict__ rowv)
{
    int bx = blockIdx.x;
    int nt = bx & 7, mt = (bx >> 3) & 31, e = bx >> 8;
    int ne = counts[e];
    if (mt * 128 >= ne) return;

    __shared__ alignas(16) char smem[18944];
    int tid = threadIdx.x, w = tid >> 6, l = tid & 63;
    float* rowsc = (float*)(smem + 18432);
    if (tid < 128) {
        int r = mt * 128 + tid;
        rowsc[tid] = (r < ne) ? sc_tmp[e * T_TOK + r] : 0.0f;
    }

    const char* gA0 = h_t + (size_t)(blk_off[e] + mt) * 1048576ull + w * 2048 + l * 16;
    const char* gA1 = gA0 + 1024;
    const char* gB0 = (const char*)w2t + ((size_t)(e * 8 + nt) * 128) * 8192
                      + w * 2048 + l * 16;
    const char* gB1 = gB0 + 1024;
    char* lA0 = smem + w * 2048;
    char* lA1 = lA0 + 1024;
    char* lB0 = smem + 8192 + w * 2048;
    char* lB1 = lB0 + 1024;

    int fr = l & 15, kq = l >> 4;
    int csel = (kq ^ ((fr >> 1) & 3)) << 4;
    int wm = (w & 1) * 64, wn = (w >> 1) * 64;
    int aoff[4], boff[4];
#pragma unroll
    for (int i = 0; i < 4; i++) {
        aoff[i] = (wm + i * 16 + fr) * 64 + csel;
        boff[i] = 8192 + (wn + i * 16 + fr) * 64 + csel;
    }

    f32x4 acc[4][4] = {};
    for (int ks = 0; ks < 128; ks++) {
        gl_lds16(gA0, lA0); gl_lds16(gA1, lA1);
        gl_lds16(gB0, lB0); gl_lds16(gB1, lB1);
        gA0 += 8192; gA1 += 8192; gB0 += 8192; gB1 += 8192;
        __syncthreads();
        bf16x8 af[4], bf[4];
#pragma unroll
        for (int i = 0; i < 4; i++) af[i] = *(const bf16x8*)(smem + aoff[i]);
#pragma unroll
        for (int i = 0; i < 4; i++) bf[i] = *(const bf16x8*)(smem + boff[i]);
#pragma unroll
        for (int mi = 0; mi < 4; mi++)
#pragma unroll
            for (int ni = 0; ni < 4; ni++)
                acc[mi][ni] = __builtin_amdgcn_mfma_f32_16x16x32_bf16(af[mi], bf[ni], acc[mi][ni], 0, 0, 0);
        __syncthreads();
    }

    // epilogue: +b2, *score, f32 rows via LDS (4 rounds of 32 cols, stride 36)
    int quad = l >> 4;
    int off_e = offsets[e];
    const float* b2e = b2 + (size_t)e * D_DIM + nt * 128;
    float* Ct = (float*)smem;
    for (int rnd = 0; rnd < 4; rnd++) {
        if ((w >> 1) == (rnd >> 1)) {
            int nb0 = (rnd & 1) * 2;
#pragma unroll
            for (int nn = 0; nn < 2; nn++) {
                int cl = nn * 16 + fr;
                float bb = b2e[rnd * 32 + cl];
#pragma unroll
                for (int mi = 0; mi < 4; mi++) {
                    int rbase = wm + mi * 16 + quad * 4;
#pragma unroll
                    for (int r = 0; r < 4; r++) {
                        int row = rbase + r;
                        Ct[row * 36 + cl] = (acc[mi][nb0 + nn][r] + bb) * rowsc[row];
                    }
                }
            }
        }
        __syncthreads();
        {
            int row = tid >> 1, h = tid & 1;
            if (mt * 128 + row < ne) {
                float* dst = rowv + (size_t)(off_e + mt * 128 + row) * D_DIM
                           + nt * 128 + rnd * 32 + h * 16;
                const float* src = Ct + row * 36 + h * 16;
#pragma unroll
                for (int j = 0; j < 4; j++)
                    *(f32x4*)(dst + j * 4) = *(const f32x4*)(src + j * 4);
            }
        }
        __syncthreads();
    }
}

// ---------------- combine (shared) ----------------
__global__ __launch_bounds__(256) void combine_k(
    const float* __restrict__ rowv, const int* __restrict__ tok2row,
    const int* __restrict__ offsets, float* __restrict__ out)
{
    int t = blockIdx.x;
    int p0 = tok2row[t*2], p1 = tok2row[t*2+1];
    int r0 = offsets[p0 >> 16] + (p0 & 0xffff);
    int r1 = offsets[p1 >> 16] + (p1 & 0xffff);
    int d = threadIdx.x * 4;
    f32x4 a = *(const f32x4*)(rowv + (size_t)r0 * D_DIM + d);
    f32x4 b = *(const f32x4*)(rowv + (size_t)r1 * D_DIM + d);
    *(f32x4*)(out + (size_t)t * D_DIM + d) = a + b;
}

// ======================= FALLBACK (round-1 GEMMs) =======================
#define BM 128
#define BN 128
#define BK 32
#define LDA 40
#define LDCB 136
#define LDCF 68
#define SMEM_BYTES 35328

__global__ __launch_bounds__(256) void ffn1_fb_k(
    const float* __restrict__ x, const float* __restrict__ w1, const float* __restrict__ b1,
    const int* __restrict__ tok_tmp, const int* __restrict__ counts,
    const int* __restrict__ offsets, bf16_t* __restrict__ h)
{
    int e  = blockIdx.x >> 5;
    int mt = blockIdx.x & 31;
    int nt = blockIdx.y;
    int ne = counts[e];
    if (mt * BM >= ne) return;
    int nb = nt * BN;
    const float* W = w1 + (size_t)e * D_DIM * F_DIM;

    __shared__ alignas(16) char smem[SMEM_BYTES];
    bf16_t* As = (bf16_t*)smem;
    bf16_t* Bs = (bf16_t*)(smem + 10240);
    int* rowtok = (int*)(smem + 34816);

    int tid = threadIdx.x;
    if (tid < 128) {
        int r = mt*BM + tid;
        rowtok[tid] = (r < ne) ? tok_tmp[e*T_TOK + r] : -1;
    }
    __syncthreads();

    f32x4 acc[4][4] = {};
    int wave = tid >> 6, lane = tid & 63;
    int wm = (wave & 1) * 64, wn = (wave >> 1) * 64;
    int fr = lane & 15, fk = (lane >> 4) * 8;
    int sr = tid >> 1, sh = (tid & 1) * 16;
    int bn_ = tid & 127, bk_ = (tid >> 7) * 16;

    for (int k0 = 0; k0 < D_DIM; k0 += BK) {
        {
            int tok = rowtok[sr];
            union { bf16_t u[16]; bf16x8 v[2]; } pk;
            if (tok >= 0) {
                const float* src = x + (size_t)tok * D_DIM + k0 + sh;
#pragma unroll
                for (int j = 0; j < 16; j++) pk.u[j] = (bf16_t)src[j];
            } else {
#pragma unroll
                for (int j = 0; j < 16; j++) pk.u[j] = (bf16_t)0.0f;
            }
            *(bf16x8*)(As + sr*LDA + sh)     = pk.v[0];
            *(bf16x8*)(As + sr*LDA + sh + 8) = pk.v[1];
        }
        {
            union { bf16_t u[16]; bf16x8 v[2]; } pk;
            const float* src = W + (size_t)(k0 + bk_) * F_DIM + nb + bn_;
#pragma unroll
            for (int j = 0; j < 16; j++) pk.u[j] = (bf16_t)src[(size_t)j * F_DIM];
            *(bf16x8*)(Bs + bn_*LDA + bk_)     = pk.v[0];
            *(bf16x8*)(Bs + bn_*LDA + bk_ + 8) = pk.v[1];
        }
        __syncthreads();
        bf16x8 af[4], bfr[4];
#pragma unroll
        for (int i = 0; i < 4; i++) af[i]  = *(bf16x8*)(As + (wm + i*16 + fr)*LDA + fk);
#pragma unroll
        for (int i = 0; i < 4; i++) bfr[i] = *(bf16x8*)(Bs + (wn + i*16 + fr)*LDA + fk);
#pragma unroll
        for (int mi = 0; mi < 4; mi++)
#pragma unroll
            for (int ni = 0; ni < 4; ni++)
                acc[mi][ni] = __builtin_amdgcn_mfma_f32_16x16x32_bf16(af[mi], bfr[ni], acc[mi][ni], 0, 0, 0);
        __syncthreads();
    }

    bf16_t* Ct = (bf16_t*)smem;
    const float* b1e = b1 + (size_t)e * F_DIM + nb;
#pragma unroll
    for (int mi = 0; mi < 4; mi++) {
        int row = wm + mi*16 + ((lane >> 4) << 2);
#pragma unroll
        for (int ni = 0; ni < 4; ni++) {
            int col = wn + ni*16 + fr;
            float bb = b1e[col];
#pragma unroll
            for (int r = 0; r < 4; r++) {
                float v = acc[mi][ni][r] + bb;
                float sv = v / (1.0f + expf(-v));
                Ct[(row + r)*LDCB + col] = (bf16_t)sv;
            }
        }
    }
    __syncthreads();
    {
        int row = tid >> 1, seg = (tid & 1) * 64;
        if (mt*BM + row < ne) {
            int grow = offsets[e] + mt*BM + row;
            bf16_t* dst = h + (size_t)grow * F_DIM + nb + seg;
#pragma unroll
            for (int j = 0; j < 8; j++)
                *(bf16x8*)(dst + j*8) = *(bf16x8*)(Ct + row*LDCB + seg + j*8);
        }
    }
}

__global__ __launch_bounds__(256) void ffn2_fb_k(
    const bf16_t* __restrict__ h, const float* __restrict__ w2, const float* __restrict__ b2,
    const float* __restrict__ sc_tmp, const int* __restrict__ counts,
    const int* __restrict__ offsets, float* __restrict__ rowv)
{
    int e  = blockIdx.x >> 5;
    int mt = blockIdx.x & 31;
    int nt = blockIdx.y;
    int ne = counts[e];
    if (mt * BM >= ne) return;
    int nb = nt * BN;
    int off = offsets[e];
    const float* W = w2 + (size_t)e * F_DIM * D_DIM;

    __shared__ alignas(16) char smem[SMEM_BYTES];
    bf16_t* As = (bf16_t*)smem;
    bf16_t* Bs = (bf16_t*)(smem + 10240);
    float* rowsc = (float*)(smem + 34816);

    int tid = threadIdx.x;
    if (tid < 128) {
        int r = mt*BM + tid;
        rowsc[tid] = (r < ne) ? sc_tmp[e*T_TOK + r] : 0.0f;
    }
    __syncthreads();

    f32x4 acc[4][4] = {};
    int wave = tid >> 6, lane = tid & 63;
    int wm = (wave & 1) * 64, wnn = wave >> 1;
    int fr = lane & 15, fk = (lane >> 4) * 8;
    int sr = tid >> 1, sh = (tid & 1) * 16;
    int bn_ = tid & 127, bk_ = (tid >> 7) * 16;
    bool arow_valid = (mt*BM + sr) < ne;
    const bf16_t* asrc0 = h + (size_t)(off + mt*BM + sr) * F_DIM + sh;

    for (int k0 = 0; k0 < F_DIM; k0 += BK) {
        {
            bf16x8 v0, v1;
            if (arow_valid) {
                v0 = *(const bf16x8*)(asrc0 + k0);
                v1 = *(const bf16x8*)(asrc0 + k0 + 8);
            } else {
                v0 = (bf16x8)(bf16_t)0.0f; v1 = (bf16x8)(bf16_t)0.0f;
            }
            *(bf16x8*)(As + sr*LDA + sh)     = v0;
            *(bf16x8*)(As + sr*LDA + sh + 8) = v1;
        }
        {
            union { bf16_t u[16]; bf16x8 v[2]; } pk;
            const float* src = W + (size_t)(k0 + bk_) * D_DIM + nb + bn_;
#pragma unroll
            for (int j = 0; j < 16; j++) pk.u[j] = (bf16_t)src[(size_t)j * D_DIM];
            *(bf16x8*)(Bs + bn_*LDA + bk_)     = pk.v[0];
            *(bf16x8*)(Bs + bn_*LDA + bk_ + 8) = pk.v[1];
        }
        __syncthreads();
        bf16x8 af[4], bfr[4];
#pragma unroll
        for (int i = 0; i < 4; i++) af[i]  = *(bf16x8*)(As + (wm + i*16 + fr)*LDA + fk);
#pragma unroll
        for (int i = 0; i < 4; i++) bfr[i] = *(bf16x8*)(Bs + (wnn*64 + i*16 + fr)*LDA + fk);
#pragma unroll
        for (int mi = 0; mi < 4; mi++)
#pragma unroll
            for (int ni = 0; ni < 4; ni++)
                acc[mi][ni] = __builtin_amdgcn_mfma_f32_16x16x32_bf16(af[mi], bfr[ni], acc[mi][ni], 0, 0, 0);
        __syncthreads();
    }

    const float* b2e = b2 + (size_t)e * D_DIM + nb;
    float* Ctf = (float*)smem;
    for (int half = 0; half < 2; half++) {
        if (wnn == half) {
#pragma unroll
            for (int mi = 0; mi < 4; mi++) {
                int row = wm + mi*16 + ((lane >> 4) << 2);
#pragma unroll
                for (int ni = 0; ni < 4; ni++) {
                    int lcol = ni*16 + fr;
                    float bb = b2e[half*64 + lcol];
#pragma unroll
                    for (int r = 0; r < 4; r++) {
                        float v = (acc[mi][ni][r] + bb) * rowsc[row + r];
                        Ctf[(row + r)*LDCF + lcol] = v;
                    }
                }
            }
        }
        __syncthreads();
        {
            int row = tid >> 1, seg = (tid & 1) * 32;
            if (mt*BM + row < ne) {
                float* dst = rowv + (size_t)(off + mt*BM + row) * D_DIM + nb + half*64 + seg;
#pragma unroll
                for (int j = 0; j < 8; j++)
                    *(f32x4*)(dst + j*4) = *(f32x4*)(Ctf + row*LDCF + seg + j*4);
            }
        }
        __syncthreads();
    }
}

// ======================= launch =======================
extern "C" void kernel_launch(void* const* d_in, const int* in_sizes, int n_in,
                              void* d_out, int out_size, void* d_ws, size_t ws_size,
                              hipStream_t stream) {
    const float* x       = (const float*)d_in[0];
    const float* noise   = (const float*)d_in[1];
    const float* gate_w  = (const float*)d_in[2];
    const float* gate_b  = (const float*)d_in[3];
    const float* noise_w = (const float*)d_in[4];
    const float* noise_b = (const float*)d_in[5];
    const float* w1      = (const float*)d_in[6];
    const float* b1      = (const float*)d_in[7];
    const float* w2      = (const float*)d_in[8];
    const float* b2      = (const float*)d_in[9];
    float* out = (float*)d_out;
    char* ws = (char*)d_ws;

    if (ws_size >= FAST_NEED) {
        bf16_t* w1t     = (bf16_t*)(ws + F_W1T);
        bf16_t* w2t     = (bf16_t*)(ws + F_W2T);
        char*   h_t     = ws + F_HT;
        bf16_t* xb      = (bf16_t*)(ws + F_XBF);
        float*  rowv    = (float*) (ws + F_ROWV);
        float*  scores  = (float*) (ws + F_SCORES);
        int*    tok_tmp = (int*)   (ws + F_TOK);
        float*  sc_tmp  = (float*) (ws + F_SC);
        int*    tok2row = (int*)   (ws + F_T2R);
        int*    counts  = (int*)   (ws + F_CNT);
        int*    offsets = (int*)   (ws + F_OFF);
        int*    blk_off = (int*)   (ws + F_BLK);

        hipMemsetAsync(ws + F_CNT, 0, 32, stream);
        router_k<<<T_TOK/4, 256, 0, stream>>>(x, noise, gate_w, gate_b, noise_w, noise_b,
                                              scores, tok_tmp, sc_tmp, tok2row, counts);
        prefix_k<<<1, 64, 0, stream>>>(counts, offsets, blk_off);
        aux_k<<<1, 256, 0, stream>>>(scores, out + (size_t)T_TOK * D_DIM);
        prep_x_k<<<2048, 256, 0, stream>>>(x, xb);
        prep_w_k<<<16384, 256, 0, stream>>>(w1, w1t, 5, 5, D_DIM, F_DIM);
        prep_w_k<<<16384, 256, 0, stream>>>(w2, w2t, 7, 3, F_DIM, D_DIM);
        ffn1_fast_k<<<8192, 256, 0, stream>>>(xb, w1t, b1, tok_tmp, counts, blk_off, h_t);
        ffn2_fast_k<<<2048, 256, 0, stream>>>(h_t, w2t, b2, sc_tmp, counts, offsets, blk_off, rowv);
        combine_k<<<T_TOK, 256, 0, stream>>>(rowv, tok2row, offsets, out);
    } else {
        bf16_t* h       = (bf16_t*)(ws + WS_H);
        float*  rowv    = (float*) (ws + WS_ROWV);
        float*  scores  = (float*) (ws + WS_SCORES);
        int*    tok_tmp = (int*)   (ws + WS_TOK);
        float*  sc_tmp  = (float*) (ws + WS_SC);
        int*    tok2row = (int*)   (ws + WS_T2R);
        int*    counts  = (int*)   (ws + WS_CNT);
        int*    offsets = (int*)   (ws + WS_OFF);
        int*    blk_off = (int*)   (ws + WS_BLK);

        hipMemsetAsync(ws + WS_CNT, 0, 32, stream);
        router_k<<<T_TOK/4, 256, 0, stream>>>(x, noise, gate_w, gate_b, noise_w, noise_b,
                                              scores, tok_tmp, sc_tmp, tok2row, counts);
        prefix_k<<<1, 64, 0, stream>>>(counts, offsets, blk_off);
        aux_k<<<1, 256, 0, stream>>>(scores, out + (size_t)T_TOK * D_DIM);
        ffn1_fb_k<<<dim3(E_NUM*32, F_DIM/BN), 256, 0, stream>>>(x, w1, b1, tok_tmp, counts, offsets, h);
        ffn2_fb_k<<<dim3(E_NUM*32, D_DIM/BN), 256, 0, stream>>>(h, w2, b2, sc_tmp, counts, offsets, rowv);
        combine_k<<<T_TOK, 256, 0, stream>>>(rowv, tok2row, offsets, out);
    }
}